// Round 1
// baseline (109.364 us; speedup 1.0000x reference)
//
#include <hip/hip_runtime.h>
#include <math.h>

// u_dot_v + sigmoid: score[e] = sigmoid(dot(h[src[e]], h[dst[e]])), D=64.
// 16 lanes cooperate per edge: lane j holds float4 j of each 256B row
// (fully coalesced 256B contiguous read per 16-lane group), then a
// 4-step shfl_xor reduction. One wave = 4 edges.

#define DOT_D 64

__global__ __launch_bounds__(256) void dot_sigmoid_kernel(
    const float* __restrict__ h,
    const int* __restrict__ src,
    const int* __restrict__ dst,
    float* __restrict__ out,
    int E)
{
    int tid  = blockIdx.x * blockDim.x + threadIdx.x;
    int lane = tid & 15;   // lane within the 16-lane edge group
    int e    = tid >> 4;   // edge index
    if (e >= E) return;

    int s = src[e];
    int d = dst[e];

    const float4* us = (const float4*)(h + (size_t)s * DOT_D);
    const float4* vs = (const float4*)(h + (size_t)d * DOT_D);
    float4 u = us[lane];
    float4 v = vs[lane];

    float p = u.x * v.x + u.y * v.y + u.z * v.z + u.w * v.w;

    // reduce across the 16-lane group (xor masks < 16 stay in-group)
    p += __shfl_xor(p, 8);
    p += __shfl_xor(p, 4);
    p += __shfl_xor(p, 2);
    p += __shfl_xor(p, 1);

    if (lane == 0) {
        out[e] = 1.0f / (1.0f + __expf(-p));
    }
}

extern "C" void kernel_launch(void* const* d_in, const int* in_sizes, int n_in,
                              void* d_out, int out_size, void* d_ws, size_t ws_size,
                              hipStream_t stream) {
    const float* h   = (const float*)d_in[0];
    const int*   src = (const int*)d_in[1];   // harness delivers integer inputs as int32
    const int*   dst = (const int*)d_in[2];
    float*       out = (float*)d_out;

    int E = in_sizes[1];
    long long total_threads = (long long)E * 16;
    int block = 256;
    int grid  = (int)((total_threads + block - 1) / block);

    dot_sigmoid_kernel<<<grid, block, 0, stream>>>(h, src, dst, out, E);
}

// Round 2
// 89.551 us; speedup vs baseline: 1.2212x; 1.2212x over previous
//
#include <hip/hip_runtime.h>
#include <hip/hip_fp16.h>
#include <math.h>

// u_dot_v + sigmoid, D=64.
// R2: pre-convert h (f32, 12.8 MB) -> fp16 (6.4 MB) in d_ws, then gather fp16
// rows. One row = 128 B = exactly one cache line; 8 lanes/edge each load 16 B
// (fully coalesced per group), dot in f32, 3-step shfl_xor reduce.
// Rationale: R1 showed 147 MB L2-miss traffic (per-XCD 4 MiB L2 can't hold
// the 12.8 MB f32 table under random gathers). Halving the table doubles L2
// hit rate and halves gather bytes.

#define DOT_D 64

__global__ __launch_bounds__(256) void f32_to_f16_kernel(
    const float* __restrict__ h, __half2* __restrict__ hh, int n4)
{
    int i = blockIdx.x * blockDim.x + threadIdx.x;
    if (i >= n4) return;
    float4 v = ((const float4*)h)[i];
    hh[2 * i]     = __floats2half2_rn(v.x, v.y);
    hh[2 * i + 1] = __floats2half2_rn(v.z, v.w);
}

__global__ __launch_bounds__(256) void dot_sigmoid_f16_kernel(
    const __half* __restrict__ h,
    const int* __restrict__ src,
    const int* __restrict__ dst,
    float* __restrict__ out,
    int E)
{
    int tid  = blockIdx.x * blockDim.x + threadIdx.x;
    int lane = tid & 7;    // 8 lanes per edge
    int e    = tid >> 3;
    if (e >= E) return;

    int s = src[e];
    int d = dst[e];

    // 16 B per lane: 8 halves. Row base is 128 B-aligned; lane*16B offsets.
    float4 ur = ((const float4*)(h + (size_t)s * DOT_D))[lane];
    float4 vr = ((const float4*)(h + (size_t)d * DOT_D))[lane];
    const __half2* up = (const __half2*)&ur;
    const __half2* vp = (const __half2*)&vr;

    float p = 0.0f;
#pragma unroll
    for (int k = 0; k < 4; ++k) {
        float2 uf = __half22float2(up[k]);
        float2 vf = __half22float2(vp[k]);
        p += uf.x * vf.x + uf.y * vf.y;
    }

    p += __shfl_xor(p, 4);
    p += __shfl_xor(p, 2);
    p += __shfl_xor(p, 1);

    if (lane == 0) {
        out[e] = 1.0f / (1.0f + __expf(-p));
    }
}

// f32 fallback (R1 kernel) if d_ws is too small for the fp16 table.
__global__ __launch_bounds__(256) void dot_sigmoid_f32_kernel(
    const float* __restrict__ h,
    const int* __restrict__ src,
    const int* __restrict__ dst,
    float* __restrict__ out,
    int E)
{
    int tid  = blockIdx.x * blockDim.x + threadIdx.x;
    int lane = tid & 15;
    int e    = tid >> 4;
    if (e >= E) return;

    int s = src[e];
    int d = dst[e];
    float4 u = ((const float4*)(h + (size_t)s * DOT_D))[lane];
    float4 v = ((const float4*)(h + (size_t)d * DOT_D))[lane];
    float p = u.x * v.x + u.y * v.y + u.z * v.z + u.w * v.w;
    p += __shfl_xor(p, 8);
    p += __shfl_xor(p, 4);
    p += __shfl_xor(p, 2);
    p += __shfl_xor(p, 1);
    if (lane == 0) out[e] = 1.0f / (1.0f + __expf(-p));
}

extern "C" void kernel_launch(void* const* d_in, const int* in_sizes, int n_in,
                              void* d_out, int out_size, void* d_ws, size_t ws_size,
                              hipStream_t stream) {
    const float* h   = (const float*)d_in[0];
    const int*   src = (const int*)d_in[1];
    const int*   dst = (const int*)d_in[2];
    float*       out = (float*)d_out;

    int ND = in_sizes[0];          // N * 64
    int E  = in_sizes[1];
    size_t f16_bytes = (size_t)ND * sizeof(__half);

    if (ws_size >= f16_bytes) {
        __half* hh = (__half*)d_ws;
        int n4 = ND / 4;
        f32_to_f16_kernel<<<(n4 + 255) / 256, 256, 0, stream>>>(h, (__half2*)hh, n4);

        long long total_threads = (long long)E * 8;
        int grid = (int)((total_threads + 255) / 256);
        dot_sigmoid_f16_kernel<<<grid, 256, 0, stream>>>(hh, src, dst, out, E);
    } else {
        long long total_threads = (long long)E * 16;
        int grid = (int)((total_threads + 255) / 256);
        dot_sigmoid_f32_kernel<<<grid, 256, 0, stream>>>(h, src, dst, out, E);
    }
}